// Round 3
// baseline (239.165 us; speedup 1.0000x reference)
//
#include <hip/hip_runtime.h>

#define N_ELEM 16777216
#define K 32                        // elements per thread-chunk
#define BLOCK 256
#define TILE (BLOCK * K)            // 8192 elements per block
#define NBLK (N_ELEM / TILE)        // 2048 blocks
#define PAD 33                      // LDS stride: conflict-free phase-B reads
#define INV_N (1.0 / (double)N_ELEM)

__global__ void k0_zero(float* __restrict__ out) { out[0] = 0.0f; }

__global__ __launch_bounds__(BLOCK) void k1_all(
        const float4* __restrict__ in4, const int2* __restrict__ lab2,
        const int* __restrict__ labs, float* __restrict__ out) {
    __shared__ float ce_lds[BLOCK * PAD];
    __shared__ float tceS[BLOCK];
    __shared__ unsigned metaS[BLOCK];   // h(6b) | firstLab<<6 | lastLab<<7
    __shared__ double wsum[BLOCK / 64];
    const int tid = threadIdx.x;
    const long long pairBase = (long long)blockIdx.x * (TILE / 2);

    // ---- phase A: coalesced global -> CE -> LDS (sign bit = label; CE > 0) ----
    #pragma unroll
    for (int j = 0; j < K / 2; ++j) {
        int p = j * BLOCK + tid;                    // pair index within tile
        float4 x = in4[pairBase + p];
        int2 lv = lab2[pairBase + p];               // labels are int32 from harness
        int l0 = lv.x, l1 = lv.y;
        float m0 = fmaxf(x.x, x.y);
        float ce0 = m0 + __logf(__expf(x.x - m0) + __expf(x.y - m0)) - (l0 ? x.y : x.x);
        float m1 = fmaxf(x.z, x.w);
        float ce1 = m1 + __logf(__expf(x.z - m1) + __expf(x.w - m1)) - (l1 ? x.w : x.z);
        int it = 2 * p;
        int q = it >> 5, off = it & 31;             // chunk-in-tile, offset
        ce_lds[q * PAD + off]     = l0 ? -ce0 : ce0;
        ce_lds[q * PAD + off + 1] = l1 ? -ce1 : ce1;
    }
    __syncthreads();

    // ---- phase B: per-thread backward scan over its contiguous 32 ----
    const int base = tid * PAD;
    double acc = 0.0;
    float tce = 0.f;
    int c = 0, prevLab = 0, lastLab = 0, lab = 0;
    #pragma unroll
    for (int i = K - 1; i >= 0; --i) {
        float v = ce_lds[base + i];
        lab = (int)(__float_as_uint(v) >> 31);
        float ce = fabsf(v);
        if (i == K - 1) { c = 1; lastLab = lab; }
        else            c = (lab == prevLab) ? c + 1 : 1;
        acc += (double)(ce * (float)c);             // local (chunk-truncated) weight
        if (c == K - i) tce += ce;                  // element is in the trailing run
        prevLab = lab;
    }
    // after loop: lab = firstLab, c = head run length h
    tceS[tid]  = tce;
    metaS[tid] = (unsigned)c | ((unsigned)lab << 6) | ((unsigned)lastLab << 7);
    __syncthreads();

    // ---- phase C: resolve trailing-run extension (expected 1 step) ----
    long long ext = 0;
    {
        int prevLast = lastLab;
        int t = tid + 1;
        bool open = true;
        while (t < BLOCK) {
            unsigned mb = metaS[t];
            if ((int)((mb >> 6) & 1) != prevLast) { open = false; break; }
            int hb = (int)(mb & 63);
            ext += hb;
            if (hb < K) { open = false; break; }    // run ends inside chunk t
            prevLast = (int)((mb >> 7) & 1);
            ++t;
        }
        if (open) {                                 // run reaches tile end (rare):
            long long g = (long long)(blockIdx.x + 1) * TILE;
            while (g < N_ELEM && labs[g] == prevLast) { ++ext; ++g; }
        }
    }
    acc += (double)tce * (double)ext;

    // ---- phase D: block reduce, one float atomic per block ----
    for (int o = 32; o; o >>= 1) acc += __shfl_down(acc, o);
    int wid = tid >> 6, lane = tid & 63;
    if (lane == 0) wsum[wid] = acc;
    __syncthreads();
    if (tid == 0) {
        double t = 0.0;
        for (int w = 0; w < BLOCK / 64; ++w) t += wsum[w];
        atomicAdd(out, (float)(t * INV_N));
    }
}

extern "C" void kernel_launch(void* const* d_in, const int* in_sizes, int n_in,
                              void* d_out, int out_size, void* d_ws, size_t ws_size,
                              hipStream_t stream) {
    const float* inputs = (const float*)d_in[0];
    const int* labels = (const int*)d_in[1];
    float* out = (float*)d_out;

    k0_zero<<<1, 1, 0, stream>>>(out);
    k1_all<<<NBLK, BLOCK, 0, stream>>>(
        (const float4*)inputs, (const int2*)labels, labels, out);
}

// Round 4
// 238.108 us; speedup vs baseline: 1.0044x; 1.0044x over previous
//
#include <hip/hip_runtime.h>

#define N_ELEM 16777216
#define K 32                        // elements per thread-chunk
#define BLOCK 256
#define TILE (BLOCK * K)            // 8192 elements per block
#define NBLK (N_ELEM / TILE)        // 2048 blocks
#define PAD 33                      // LDS stride (ushort units): 2-way aliasing = free
#define INV_N (1.0 / (double)N_ELEM)

__global__ void k0_zero(float* __restrict__ out) { out[0] = 0.0f; }

__device__ __forceinline__ unsigned f32_to_bf16_rne(float f) {
    unsigned b = __float_as_uint(f);
    return (b + 0x7FFFu + ((b >> 16) & 1u)) >> 16;
}

__global__ __launch_bounds__(BLOCK) void k1_all(
        const float4* __restrict__ in4, const int2* __restrict__ lab2,
        const int* __restrict__ labs, float* __restrict__ out) {
    __shared__ unsigned short ce_lds[BLOCK * PAD];  // bf16 CE, sign bit = label
    __shared__ unsigned metaS[BLOCK];               // h(6b) | firstLab<<6 | lastLab<<7
    __shared__ double wsum[BLOCK / 64];
    const int tid = threadIdx.x;
    const long long pairBase = (long long)blockIdx.x * (TILE / 2);

    // ---- phase A: coalesced global -> CE=softplus(x_o - x_l) -> LDS bf16 ----
    #pragma unroll
    for (int j = 0; j < K / 2; ++j) {
        int p = j * BLOCK + tid;                    // pair index within tile
        float4 x = in4[pairBase + p];
        int2 lv = lab2[pairBase + p];               // labels arrive as int32
        int l0 = lv.x, l1 = lv.y;
        float t0 = x.y - x.x;                       // x1 - x0
        float d0 = l0 ? -t0 : t0;                   // x_other - x_label
        float ce0 = __logf(1.0f + __expf(d0));
        float t1 = x.w - x.z;
        float d1 = l1 ? -t1 : t1;
        float ce1 = __logf(1.0f + __expf(d1));
        int it = 2 * p;
        int q = it >> 5, off = it & 31;             // chunk-in-tile, offset
        ce_lds[q * PAD + off]     = (unsigned short)(f32_to_bf16_rne(ce0) | ((unsigned)l0 << 15));
        ce_lds[q * PAD + off + 1] = (unsigned short)(f32_to_bf16_rne(ce1) | ((unsigned)l1 << 15));
    }
    __syncthreads();

    // ---- phase B: per-thread backward scan over its contiguous 32 (registers) ----
    const int base = tid * PAD;
    float acc = 0.f, tce = 0.f;
    int c = 0, prevLab = 0, lastLab = 0, lab = 0;
    #pragma unroll
    for (int i = K - 1; i >= 0; --i) {
        unsigned u = ce_lds[base + i];
        lab = (int)(u >> 15);
        float ce = __uint_as_float((u & 0x7FFFu) << 16);
        if (i == K - 1) { c = 1; lastLab = lab; }
        else            c = (lab == prevLab) ? c + 1 : 1;
        acc = fmaf(ce, (float)c, acc);              // local (chunk-truncated) weight
        if (c == K - i) tce += ce;                  // element is in the trailing run
        prevLab = lab;
    }
    // after loop: lab = firstLab, c = head run length h
    metaS[tid] = (unsigned)c | ((unsigned)lab << 6) | ((unsigned)lastLab << 7);
    __syncthreads();

    // ---- phase C: resolve trailing-run extension (expected 1 step) ----
    long long ext = 0;
    {
        int prevLast = lastLab;
        int t = tid + 1;
        bool open = true;
        while (t < BLOCK) {
            unsigned mb = metaS[t];
            if ((int)((mb >> 6) & 1) != prevLast) { open = false; break; }
            int hb = (int)(mb & 63);
            ext += hb;
            if (hb < K) { open = false; break; }    // run ends inside chunk t
            prevLast = (int)((mb >> 7) & 1);
            ++t;
        }
        if (open) {                                 // run reaches tile end (rare)
            long long g = (long long)(blockIdx.x + 1) * TILE;
            while (g < N_ELEM && labs[g] == prevLast) { ++ext; ++g; }
        }
    }
    double accd = (double)acc + (double)tce * (double)ext;

    // ---- phase D: block reduce, one float atomic per block ----
    for (int o = 32; o; o >>= 1) accd += __shfl_down(accd, o);
    int wid = tid >> 6, lane = tid & 63;
    if (lane == 0) wsum[wid] = accd;
    __syncthreads();
    if (tid == 0) {
        double t = 0.0;
        for (int w = 0; w < BLOCK / 64; ++w) t += wsum[w];
        atomicAdd(out, (float)(t * INV_N));
    }
}

extern "C" void kernel_launch(void* const* d_in, const int* in_sizes, int n_in,
                              void* d_out, int out_size, void* d_ws, size_t ws_size,
                              hipStream_t stream) {
    const float* inputs = (const float*)d_in[0];
    const int* labels = (const int*)d_in[1];
    float* out = (float*)d_out;

    k0_zero<<<1, 1, 0, stream>>>(out);
    k1_all<<<NBLK, BLOCK, 0, stream>>>(
        (const float4*)inputs, (const int2*)labels, labels, out);
}